// Round 7
// baseline (190.564 us; speedup 1.0000x reference)
//
#include <hip/hip_runtime.h>
#include <hip/hip_bf16.h>

// GraphAttentionLayer: B=8,N=1024,FIN=E=OUT=128,NH=8,HD=16. f32 in/out.
// R32: flash_mfma rewritten (other 3 kernels byte-identical to R30, 159.75us).
// R31 isolated flash ~= 18-22us. Changes: (1) KVBLK 64->128: 8 stages (was
// 16); (2) double-buffered LDS 2x36.2KB=72.4KB -> ONE barrier/stage (8 vs 32;
// safe: stage st writes buf st&1, barrier, computes it; stage st+1 writes the
// OTHER buffer -- all reads of that buffer ended before the barrier of stage
// st); (3) T14 prefetch: stage st+1's 8 uint4 global loads issued into regs
// before the barrier of stage st -> latency hidden under MFMA+exp compute.
// Key order unchanged (8x8 == 16x4 ascending) -> bit-identical accumulation;
// absmax must stay exactly 9.155273e-05. 2 blk/CU kept (144.9KB < 160KB LDS).

using u16 = unsigned short;
typedef short bf16x8 __attribute__((ext_vector_type(8)));
typedef float f32x4 __attribute__((ext_vector_type(4)));
typedef _Float16 f16;
typedef _Float16 f16x4 __attribute__((ext_vector_type(4)));

#define MFMA16(a, b, c) __builtin_amdgcn_mfma_f32_16x16x16f16(a, b, c, 0, 0, 0)
#define MFMAB(a, b, c) __builtin_amdgcn_mfma_f32_16x16x32_bf16(a, b, c, 0, 0, 0)

__device__ __forceinline__ u16 f2b(float f) {
    unsigned u = __float_as_uint(f);
    return (u16)((u + 0x7fffu + ((u >> 16) & 1u)) >> 16);  // RNE
}
__device__ __forceinline__ float b2f(u16 u) {
    return __uint_as_float(((unsigned)u) << 16);
}

// ---- merged prep + Hp-GEMM (byte-identical to R30) ----
__global__ void prep_hp(const float* __restrict__ H, const float* __restrict__ Wlin,
                        const float* __restrict__ Win,
                        const float* __restrict__ Wout, const float* __restrict__ Wfin,
                        const float* __restrict__ bout, const float* __restrict__ bfin,
                        const float* __restrict__ blin,
                        u16* __restrict__ WinTb, u16* __restrict__ WcombTb,
                        float* __restrict__ bcomb, float* __restrict__ rowsum,
                        u16* __restrict__ Hpb) {
    if (blockIdx.x < 64) {
        const int m0 = blockIdx.x * 128;
        const int t = threadIdx.x;
        const int wave = t >> 6, lane = t & 63;
        const int wm = (wave >> 1) * 64, wn = (wave & 1) * 64;
        const int m16 = lane & 15, kq = lane >> 4;
        f32x4 acc[4][4] = {};

#pragma unroll
        for (int kc = 0; kc < 4; ++kc) {
            bf16x8 af[4], bf[4];
#pragma unroll
            for (int i = 0; i < 4; ++i) {
                const float* ap = &H[(long long)(m0 + wm + i * 16 + m16) * 128 + kc * 32 + kq * 8];
                float4 u0 = *(const float4*)ap;
                float4 u1 = *(const float4*)(ap + 4);
                bf16x8 a;
                a[0] = (short)f2b(u0.x); a[1] = (short)f2b(u0.y);
                a[2] = (short)f2b(u0.z); a[3] = (short)f2b(u0.w);
                a[4] = (short)f2b(u1.x); a[5] = (short)f2b(u1.y);
                a[6] = (short)f2b(u1.z); a[7] = (short)f2b(u1.w);
                af[i] = a;
            }
#pragma unroll
            for (int j = 0; j < 4; ++j) {
                const int col = wn + j * 16 + m16;
                const int k0 = kc * 32 + kq * 8;
                bf16x8 bb;
#pragma unroll
                for (int e = 0; e < 8; ++e)
                    bb[e] = (short)f2b(Wlin[(long long)(k0 + e) * 128 + col]);
                bf[j] = bb;
            }
#pragma unroll
            for (int i = 0; i < 4; ++i)
#pragma unroll
                for (int j = 0; j < 4; ++j)
                    acc[i][j] = MFMAB(af[i], bf[j], acc[i][j]);
        }
#pragma unroll
        for (int i = 0; i < 4; ++i) {
#pragma unroll
            for (int r = 0; r < 4; ++r) {
                long long row = m0 + wm + i * 16 + kq * 4 + r;
#pragma unroll
                for (int j = 0; j < 4; ++j) {
                    int col = wn + j * 16 + m16;
                    Hpb[row * 128 + col] = f2b(acc[i][j][r] + blin[col]);
                }
            }
        }
        return;
    }
    int i = (blockIdx.x - 64) * 256 + threadIdx.x;   // 0..81919
    if (i < 8192) rowsum[i] = 0.f;
    if (i >= 16384 && i < 65536) {
        int k = i - 16384;                    // Win 128x384 -> WinTb 384x128 bf16
        int r = k / 384, c = k - r * 384;
        WinTb[c * 128 + r] = f2b(Win[k]);
    } else if (i >= 65536) {
        int k = i - 65536;
        int o = k & 127, e = k >> 7;          // o fastest: Wfin coalesced
        float s = 0.f;
        for (int kk = 0; kk < 128; ++kk)
            s = fmaf(Wout[e * 128 + kk], Wfin[kk * 128 + o], s);
        WcombTb[o * 128 + e] = f2b(s);
        if (e == 0) {
            float sb = bfin[o];
            for (int kk = 0; kk < 128; ++kk)
                sb = fmaf(bout[kk], Wfin[kk * 128 + o], sb);
            bcomb[o] = sb;
        }
    }
}

// ---- merged qkvz (byte-identical to R30) ----
__global__ __launch_bounds__(256)
void mfma_qkvz(const u16* __restrict__ Hpb, const u16* __restrict__ WinTb,
               const float* __restrict__ bin, f16* __restrict__ Cq,
               const float* __restrict__ Aadj, u16* __restrict__ EZ,
               float* __restrict__ rowsum) {
    const int blk = blockIdx.x;
    const int t = threadIdx.x;
    const int wave = t >> 6, lane = t & 63;
    const int wm = (wave >> 1) * 64, wn = (wave & 1) * 64;
    const int m16 = lane & 15, kq = lane >> 4;
    f32x4 acc[4][4] = {};

    if (blk < 512) {
        const int b = blk >> 6, mt = (blk >> 3) & 7, nt = blk & 7;
        const u16* Ab = Hpb + (long long)b * 1024 * 128;
        const int m0 = mt * 128, n0 = nt * 128;
#pragma unroll
        for (int kc = 0; kc < 4; ++kc) {
            bf16x8 af[4], bf[4];
#pragma unroll
            for (int i = 0; i < 4; ++i)
                af[i] = *(const bf16x8*)&Ab[(long long)(m0 + wm + i * 16 + m16) * 128 + kc * 32 + kq * 8];
#pragma unroll
            for (int j = 0; j < 4; ++j)
                bf[j] = *(const bf16x8*)&Ab[(long long)(n0 + wn + j * 16 + m16) * 128 + kc * 32 + kq * 8];
#pragma unroll
            for (int i = 0; i < 4; ++i)
#pragma unroll
                for (int j = 0; j < 4; ++j)
                    acc[i][j] = MFMAB(af[i], bf[j], acc[i][j]);
        }
        const long long zb = (long long)b * 1024 * 1024;
#pragma unroll
        for (int i = 0; i < 4; ++i) {
#pragma unroll
            for (int r = 0; r < 4; ++r) {
                int row = m0 + wm + i * 16 + kq * 4 + r;
                float es = 0.f;
#pragma unroll
                for (int j = 0; j < 4; ++j) {
                    int col = n0 + wn + j * 16 + m16;
                    float v = acc[i][j][r];
                    v = v >= 0.f ? v : 0.2f * v;                    // LeakyReLU(0.2)
                    if (Aadj[zb + (long long)row * 1024 + col] == 0.f) v = 0.f;  // gate
                    float ev = __expf(v);                           // m=0: |z| bounded
                    EZ[zb + (long long)row * 1024 + col] = f2b(ev);
                    es += ev;
                }
#pragma unroll
                for (int off = 1; off < 16; off <<= 1) es += __shfl_xor(es, off);
                if (m16 == 0) atomicAdd(&rowsum[b * 1024 + row], es);
            }
        }
    } else {
        const int q = blk - 512;
        const int mt = q & 63, slab = q >> 6;   // 0=q, 1=k, 2=v
        const int m0 = mt * 128;
        const u16* Bslab = WinTb + (long long)slab * 128 * 128;
#pragma unroll
        for (int kc = 0; kc < 4; ++kc) {
            bf16x8 af[4], bf[4];
#pragma unroll
            for (int i = 0; i < 4; ++i)
                af[i] = *(const bf16x8*)&Hpb[(long long)(m0 + wm + i * 16 + m16) * 128 + kc * 32 + kq * 8];
#pragma unroll
            for (int j = 0; j < 4; ++j)
                bf[j] = *(const bf16x8*)&Bslab[(long long)(wn + j * 16 + m16) * 128 + kc * 32 + kq * 8];
#pragma unroll
            for (int i = 0; i < 4; ++i)
#pragma unroll
                for (int j = 0; j < 4; ++j)
                    acc[i][j] = MFMAB(af[i], bf[j], acc[i][j]);
        }
        const float qscale = (slab == 0) ? 0.25f : 1.f;   // fold 1/sqrt(HD) into q
#pragma unroll
        for (int i = 0; i < 4; ++i) {
#pragma unroll
            for (int r = 0; r < 4; ++r) {
                long long row = m0 + wm + i * 16 + kq * 4 + r;
#pragma unroll
                for (int j = 0; j < 4; ++j) {
                    int col = wn + j * 16 + m16;
                    float v = (acc[i][j][r] + bin[slab * 128 + col]) * qscale;
                    Cq[row * 384 + slab * 128 + col] = (f16)v;
                }
            }
        }
    }
}

// ---- flash v2: 8 stages of 128 keys, double-buffered LDS, 1 barrier/stage,
//      prefetch-into-regs. Same key order as v1 -> bit-identical output. ----
__global__ __launch_bounds__(256)
void flash_mfma(const f16* __restrict__ qkv, const u16* __restrict__ ez,
                const float* __restrict__ rowsum, u16* __restrict__ ob) {
    const int n0 = blockIdx.x * 64;
    const int b = blockIdx.y;
    const int h0 = blockIdx.z * 2;       // 2 heads per block
    const int t = threadIdx.x;
    const int w = t >> 6, lane = t & 63;
    const int qr16 = lane & 15, quad = lane >> 4;

    __shared__ u16 Ks[2][128 * 40];    // [buf][key][dim 0..31 of head pair]
    __shared__ u16 VTs[2][32 * 134];   // [buf][dim][key]; 134 -> 67-dword row
                                       // step == 3 mod 32: 16 lanes conflict-free
    __shared__ u16 AWs[2][64 * 136];   // [buf][qrow][key 0..127] bf16 (ez)

    const int qrow_l = w * 16 + qr16;                 // block-local qrow
    const long long qrow_g = b * 1024 + n0 + qrow_l;  // global qrow
    const float inv0 = 1.f / rowsum[qrow_g];

    f16x4 qf[2];
#pragma unroll
    for (int hh = 0; hh < 2; ++hh)
        qf[hh] = *(const f16x4*)&qkv[qrow_g * 384 + (h0 + hh) * 16 + quad * 4];

    f32x4 accO[2] = {};
    float lacc[2] = {0.f, 0.f};

    // staging thread roles (fixed across stages)
    const int key0 = t >> 2, c8 = t & 3;   // K/V: keys key0, key0+64; dims c8*8..+7
    const int awr = t >> 4, awc = t & 15;  // AW: rows awr+{0,16,32,48}; cols awc*8..+7

    uint4 kreg[2], vreg[2], awreg[4];
#define FLASH_ISSUE(ST)                                                              \
    {                                                                                \
        const int kb_ = (ST) * 128;                                                  \
        _Pragma("unroll")                                                            \
        for (int kk = 0; kk < 2; ++kk) {                                             \
            const long long kr = (long long)(b * 1024 + kb_ + key0 + kk * 64) * 384; \
            kreg[kk] = *(const uint4*)&qkv[kr + 128 + h0 * 16 + c8 * 8];             \
            vreg[kk] = *(const uint4*)&qkv[kr + 256 + h0 * 16 + c8 * 8];             \
        }                                                                            \
        _Pragma("unroll")                                                            \
        for (int rr = 0; rr < 4; ++rr)                                               \
            awreg[rr] = *(const uint4*)&ez[((long long)(b * 1024 + n0 + awr + rr * 16)) * 1024 + kb_ + awc * 8]; \
    }

    FLASH_ISSUE(0)
    for (int st = 0; st < 8; ++st) {
        const int bu = st & 1;
        // regs -> LDS[bu] (compiler inserts vmcnt wait on the prefetch loads)
#pragma unroll
        for (int kk = 0; kk < 2; ++kk) {
            *(uint4*)&Ks[bu][(key0 + kk * 64) * 40 + c8 * 8] = kreg[kk];
            const u16* vp = (const u16*)&vreg[kk];
            const int d0 = c8 * 8, key = key0 + kk * 64;
#pragma unroll
            for (int i = 0; i < 8; ++i)
                VTs[bu][(d0 + i) * 134 + key] = vp[i];
        }
#pragma unroll
        for (int rr = 0; rr < 4; ++rr)
            *(uint4*)&AWs[bu][(awr + rr * 16) * 136 + awc * 8] = awreg[rr];
        if (st < 7) FLASH_ISSUE(st + 1)
        __syncthreads();

#pragma unroll 2
        for (int kt = 0; kt < 8; ++kt) {
            // aw C-init: lane holds (qrow=qr16, keys kt*16+quad*4+r)
            ushort4 ue = *(const ushort4*)&AWs[bu][qrow_l * 136 + kt * 16 + quad * 4];
            f32x4 aw0;
            aw0[0] = b2f(ue.x) * inv0; aw0[1] = b2f(ue.y) * inv0;
            aw0[2] = b2f(ue.z) * inv0; aw0[3] = b2f(ue.w) * inv0;
#pragma unroll
            for (int hh = 0; hh < 2; ++hh) {
                f16x4 kf = *(const f16x4*)&Ks[bu][(kt * 16 + qr16) * 40 + hh * 16 + quad * 4];
                f32x4 s4 = MFMA16(kf, qf[hh], aw0);
                float p0 = __expf(s4[0]), p1 = __expf(s4[1]);
                float p2 = __expf(s4[2]), p3 = __expf(s4[3]);
                lacc[hh] += (p0 + p1) + (p2 + p3);
                f16x4 pf;
                pf[0] = (f16)p0; pf[1] = (f16)p1; pf[2] = (f16)p2; pf[3] = (f16)p3;
                f16x4 vf = *(const f16x4*)&VTs[bu][(hh * 16 + qr16) * 134 + kt * 16 + quad * 4];
                accO[hh] = MFMA16(vf, pf, accO[hh]);
            }
        }
        // no trailing barrier: next stage writes the OTHER buffer, whose
        // readers all finished before this stage's barrier.
    }
    // finalize: l over quads, store o normalized as bf16
#pragma unroll
    for (int hh = 0; hh < 2; ++hh) {
        float l = lacc[hh];
        l += __shfl_xor(l, 16);
        l += __shfl_xor(l, 32);
        float inv = 1.f / l;
        ushort4 st4;
        st4.x = f2b(accO[hh][0] * inv);
        st4.y = f2b(accO[hh][1] * inv);
        st4.z = f2b(accO[hh][2] * inv);
        st4.w = f2b(accO[hh][3] * inv);
        *(ushort4*)&ob[qrow_g * 128 + (h0 + hh) * 16 + quad * 4] = st4;
    }
#undef FLASH_ISSUE
}

// -------- out = ob @ WcombTb^T + bcomb (byte-identical to R30) --------
__global__ __launch_bounds__(256)
void mfma_out(const u16* __restrict__ A, const u16* __restrict__ Bb,
              const float* __restrict__ bias, float* __restrict__ C) {
    const int m0 = blockIdx.x * 128;
    const int t = threadIdx.x;
    const int wave = t >> 6, lane = t & 63;
    const int wm = (wave >> 1) * 64, wn = (wave & 1) * 64;
    const int m16 = lane & 15, kq = lane >> 4;
    f32x4 acc[4][4] = {};

#pragma unroll
    for (int kc = 0; kc < 4; ++kc) {
        bf16x8 af[4], bf[4];
#pragma unroll
        for (int i = 0; i < 4; ++i)
            af[i] = *(const bf16x8*)&A[(long long)(m0 + wm + i * 16 + m16) * 128 + kc * 32 + kq * 8];
#pragma unroll
        for (int j = 0; j < 4; ++j)
            bf[j] = *(const bf16x8*)&Bb[(long long)(wn + j * 16 + m16) * 128 + kc * 32 + kq * 8];
#pragma unroll
        for (int i = 0; i < 4; ++i)
#pragma unroll
            for (int j = 0; j < 4; ++j)
                acc[i][j] = MFMAB(af[i], bf[j], acc[i][j]);
    }
#pragma unroll
    for (int i = 0; i < 4; ++i) {
#pragma unroll
        for (int r = 0; r < 4; ++r) {
            long long row = m0 + wm + i * 16 + kq * 4 + r;
#pragma unroll
            for (int j = 0; j < 4; ++j) {
                int col = wn + j * 16 + m16;
                C[row * 128 + col] = acc[i][j][r] + bias[col];
            }
        }
    }
}

extern "C" void kernel_launch(void* const* d_in, const int* in_sizes, int n_in,
                              void* d_out, int out_size, void* d_ws, size_t ws_size,
                              hipStream_t stream) {
    (void)in_sizes; (void)n_in; (void)out_size; (void)ws_size;
    const float* H    = (const float*)d_in[0];
    const float* Aadj = (const float*)d_in[1];
    const float* Wlin = (const float*)d_in[2];
    const float* blin = (const float*)d_in[3];
    const float* Win  = (const float*)d_in[4];
    const float* bin  = (const float*)d_in[5];
    const float* Wout = (const float*)d_in[6];
    const float* bout = (const float*)d_in[7];
    const float* Wfin = (const float*)d_in[8];
    const float* bfin = (const float*)d_in[9];
    float* out = (float*)d_out;
    char* ws = (char*)d_ws;

    u16*   WinTb   = (u16*)(ws + 0);          // 96 KB bf16
    u16*   WcombTb = (u16*)(ws + 98304);      // 32 KB bf16
    float* bcomb   = (float*)(ws + 131072);   // 512 B
    float* rowsum  = (float*)(ws + 131584);   // 32 KB
    u16*   Hpb     = (u16*)(ws + 262144);     // 2 MB bf16
    f16*   qkv     = (f16*)(ws + 2359296);    // 6 MB (q f16*0.25 | k f16 | v f16)
    u16*   ob      = (u16*)(ws + 8650752);    // 2 MB bf16 normalized o
    u16*   ez      = (u16*)(ws + 12845056);   // 16 MB bf16 exp(z)
    // total ~29 MB

    // prep: Hp MFMA (64 blocks) + weight transposes/combine (320 blocks)
    prep_hp<<<384, 256, 0, stream>>>(H, Wlin, Win, Wout, Wfin, bout, bfin,
                                     blin, WinTb, WcombTb, bcomb, rowsum, Hpb);
    // merged: ez-gate (512 blocks, direct Aadj gate) + qkv f16 (192 blocks)
    mfma_qkvz<<<704, 256, 0, stream>>>(Hpb, WinTb, bin, qkv, Aadj, ez, rowsum);
    // flash v2 (8x128-key stages, dbuf LDS, 1 barrier/stage, prefetch)
    flash_mfma<<<dim3(16, 8, 4), 256, 0, stream>>>(qkv, ez, rowsum, ob);
    // out = ob @ WcombTb^T + bcomb  (MFMA)
    mfma_out<<<64, 256, 0, stream>>>(ob, WcombTb, bcomb, out);
}

// Round 8
// 157.583 us; speedup vs baseline: 1.2093x; 1.2093x over previous
//
#include <hip/hip_runtime.h>
#include <hip/hip_bf16.h>

// GraphAttentionLayer: B=8,N=1024,FIN=E=OUT=128,NH=8,HD=16. f32 in/out.
// R33: flash v2 REVERTED (61us vs v1's 30us: fetch/latency-bound, not
// barrier-bound; 80KB LDS + lockstep vmcnt(0) prefetch was a net loss).
// All four kernels byte-identical to R30 (159.75us) EXCEPT flash's grid
// mapping: 1D 512 with XCD swizzle bid = xcd + 8*(4*g + hpair) so the 4
// hpair blocks sharing one (qblk,b) ez slice (128KB) land consecutively on
// the SAME XCD (bid%8 round-robin assumption) -> ez fetched once into that
// XCD's L2, shared by 4 blocks. Kills the 4x ez redundancy behind flash's
// 36MB FETCH. Math bit-identical -> absmax must stay exactly 9.155273e-05.

using u16 = unsigned short;
typedef short bf16x8 __attribute__((ext_vector_type(8)));
typedef float f32x4 __attribute__((ext_vector_type(4)));
typedef _Float16 f16;
typedef _Float16 f16x4 __attribute__((ext_vector_type(4)));

#define MFMA16(a, b, c) __builtin_amdgcn_mfma_f32_16x16x16f16(a, b, c, 0, 0, 0)
#define MFMAB(a, b, c) __builtin_amdgcn_mfma_f32_16x16x32_bf16(a, b, c, 0, 0, 0)

__device__ __forceinline__ u16 f2b(float f) {
    unsigned u = __float_as_uint(f);
    return (u16)((u + 0x7fffu + ((u >> 16) & 1u)) >> 16);  // RNE
}
__device__ __forceinline__ float b2f(u16 u) {
    return __uint_as_float(((unsigned)u) << 16);
}

// ---- merged prep + Hp-GEMM (byte-identical to R30) ----
__global__ void prep_hp(const float* __restrict__ H, const float* __restrict__ Wlin,
                        const float* __restrict__ Win,
                        const float* __restrict__ Wout, const float* __restrict__ Wfin,
                        const float* __restrict__ bout, const float* __restrict__ bfin,
                        const float* __restrict__ blin,
                        u16* __restrict__ WinTb, u16* __restrict__ WcombTb,
                        float* __restrict__ bcomb, float* __restrict__ rowsum,
                        u16* __restrict__ Hpb) {
    if (blockIdx.x < 64) {
        const int m0 = blockIdx.x * 128;
        const int t = threadIdx.x;
        const int wave = t >> 6, lane = t & 63;
        const int wm = (wave >> 1) * 64, wn = (wave & 1) * 64;
        const int m16 = lane & 15, kq = lane >> 4;
        f32x4 acc[4][4] = {};

#pragma unroll
        for (int kc = 0; kc < 4; ++kc) {
            bf16x8 af[4], bf[4];
#pragma unroll
            for (int i = 0; i < 4; ++i) {
                const float* ap = &H[(long long)(m0 + wm + i * 16 + m16) * 128 + kc * 32 + kq * 8];
                float4 u0 = *(const float4*)ap;
                float4 u1 = *(const float4*)(ap + 4);
                bf16x8 a;
                a[0] = (short)f2b(u0.x); a[1] = (short)f2b(u0.y);
                a[2] = (short)f2b(u0.z); a[3] = (short)f2b(u0.w);
                a[4] = (short)f2b(u1.x); a[5] = (short)f2b(u1.y);
                a[6] = (short)f2b(u1.z); a[7] = (short)f2b(u1.w);
                af[i] = a;
            }
#pragma unroll
            for (int j = 0; j < 4; ++j) {
                const int col = wn + j * 16 + m16;
                const int k0 = kc * 32 + kq * 8;
                bf16x8 bb;
#pragma unroll
                for (int e = 0; e < 8; ++e)
                    bb[e] = (short)f2b(Wlin[(long long)(k0 + e) * 128 + col]);
                bf[j] = bb;
            }
#pragma unroll
            for (int i = 0; i < 4; ++i)
#pragma unroll
                for (int j = 0; j < 4; ++j)
                    acc[i][j] = MFMAB(af[i], bf[j], acc[i][j]);
        }
#pragma unroll
        for (int i = 0; i < 4; ++i) {
#pragma unroll
            for (int r = 0; r < 4; ++r) {
                long long row = m0 + wm + i * 16 + kq * 4 + r;
#pragma unroll
                for (int j = 0; j < 4; ++j) {
                    int col = wn + j * 16 + m16;
                    Hpb[row * 128 + col] = f2b(acc[i][j][r] + blin[col]);
                }
            }
        }
        return;
    }
    int i = (blockIdx.x - 64) * 256 + threadIdx.x;   // 0..81919
    if (i < 8192) rowsum[i] = 0.f;
    if (i >= 16384 && i < 65536) {
        int k = i - 16384;                    // Win 128x384 -> WinTb 384x128 bf16
        int r = k / 384, c = k - r * 384;
        WinTb[c * 128 + r] = f2b(Win[k]);
    } else if (i >= 65536) {
        int k = i - 65536;
        int o = k & 127, e = k >> 7;          // o fastest: Wfin coalesced
        float s = 0.f;
        for (int kk = 0; kk < 128; ++kk)
            s = fmaf(Wout[e * 128 + kk], Wfin[kk * 128 + o], s);
        WcombTb[o * 128 + e] = f2b(s);
        if (e == 0) {
            float sb = bfin[o];
            for (int kk = 0; kk < 128; ++kk)
                sb = fmaf(bout[kk], Wfin[kk * 128 + o], sb);
            bcomb[o] = sb;
        }
    }
}

// ---- merged qkvz (byte-identical to R30) ----
__global__ __launch_bounds__(256)
void mfma_qkvz(const u16* __restrict__ Hpb, const u16* __restrict__ WinTb,
               const float* __restrict__ bin, f16* __restrict__ Cq,
               const float* __restrict__ Aadj, u16* __restrict__ EZ,
               float* __restrict__ rowsum) {
    const int blk = blockIdx.x;
    const int t = threadIdx.x;
    const int wave = t >> 6, lane = t & 63;
    const int wm = (wave >> 1) * 64, wn = (wave & 1) * 64;
    const int m16 = lane & 15, kq = lane >> 4;
    f32x4 acc[4][4] = {};

    if (blk < 512) {
        const int b = blk >> 6, mt = (blk >> 3) & 7, nt = blk & 7;
        const u16* Ab = Hpb + (long long)b * 1024 * 128;
        const int m0 = mt * 128, n0 = nt * 128;
#pragma unroll
        for (int kc = 0; kc < 4; ++kc) {
            bf16x8 af[4], bf[4];
#pragma unroll
            for (int i = 0; i < 4; ++i)
                af[i] = *(const bf16x8*)&Ab[(long long)(m0 + wm + i * 16 + m16) * 128 + kc * 32 + kq * 8];
#pragma unroll
            for (int j = 0; j < 4; ++j)
                bf[j] = *(const bf16x8*)&Ab[(long long)(n0 + wn + j * 16 + m16) * 128 + kc * 32 + kq * 8];
#pragma unroll
            for (int i = 0; i < 4; ++i)
#pragma unroll
                for (int j = 0; j < 4; ++j)
                    acc[i][j] = MFMAB(af[i], bf[j], acc[i][j]);
        }
        const long long zb = (long long)b * 1024 * 1024;
#pragma unroll
        for (int i = 0; i < 4; ++i) {
#pragma unroll
            for (int r = 0; r < 4; ++r) {
                int row = m0 + wm + i * 16 + kq * 4 + r;
                float es = 0.f;
#pragma unroll
                for (int j = 0; j < 4; ++j) {
                    int col = n0 + wn + j * 16 + m16;
                    float v = acc[i][j][r];
                    v = v >= 0.f ? v : 0.2f * v;                    // LeakyReLU(0.2)
                    if (Aadj[zb + (long long)row * 1024 + col] == 0.f) v = 0.f;  // gate
                    float ev = __expf(v);                           // m=0: |z| bounded
                    EZ[zb + (long long)row * 1024 + col] = f2b(ev);
                    es += ev;
                }
#pragma unroll
                for (int off = 1; off < 16; off <<= 1) es += __shfl_xor(es, off);
                if (m16 == 0) atomicAdd(&rowsum[b * 1024 + row], es);
            }
        }
    } else {
        const int q = blk - 512;
        const int mt = q & 63, slab = q >> 6;   // 0=q, 1=k, 2=v
        const int m0 = mt * 128;
        const u16* Bslab = WinTb + (long long)slab * 128 * 128;
#pragma unroll
        for (int kc = 0; kc < 4; ++kc) {
            bf16x8 af[4], bf[4];
#pragma unroll
            for (int i = 0; i < 4; ++i)
                af[i] = *(const bf16x8*)&Hpb[(long long)(m0 + wm + i * 16 + m16) * 128 + kc * 32 + kq * 8];
#pragma unroll
            for (int j = 0; j < 4; ++j)
                bf[j] = *(const bf16x8*)&Bslab[(long long)(wn + j * 16 + m16) * 128 + kc * 32 + kq * 8];
#pragma unroll
            for (int i = 0; i < 4; ++i)
#pragma unroll
                for (int j = 0; j < 4; ++j)
                    acc[i][j] = MFMAB(af[i], bf[j], acc[i][j]);
        }
        const float qscale = (slab == 0) ? 0.25f : 1.f;   // fold 1/sqrt(HD) into q
#pragma unroll
        for (int i = 0; i < 4; ++i) {
#pragma unroll
            for (int r = 0; r < 4; ++r) {
                long long row = m0 + wm + i * 16 + kq * 4 + r;
#pragma unroll
                for (int j = 0; j < 4; ++j) {
                    int col = wn + j * 16 + m16;
                    float v = (acc[i][j][r] + bin[slab * 128 + col]) * qscale;
                    Cq[row * 384 + slab * 128 + col] = (f16)v;
                }
            }
        }
    }
}

// ---- flash (MFMA): v1 body (= R30), XCD-swizzled 1D grid of 512.
// bid = xcd + 8*(4*g + hpair): the 4 hpair siblings of one (qblk,b) are
// consecutive slots on ONE XCD -> shared 128KB ez slice hits L2. ----
__global__ __launch_bounds__(256)
void flash_mfma(const f16* __restrict__ qkv, const u16* __restrict__ ez,
                const float* __restrict__ rowsum, u16* __restrict__ ob) {
    const int bid = blockIdx.x;
    const int xcd = bid & 7;
    const int rr_ = bid >> 3;
    const int hpair = rr_ & 3;
    const int g = rr_ >> 2;
    const int pair = g * 8 + xcd;        // 0..127 = (b, qblk)
    const int n0 = (pair & 15) * 64;     // qblk
    const int b = pair >> 4;             // batch
    const int h0 = hpair * 2;            // 2 heads per block
    const int t = threadIdx.x;
    const int w = t >> 6, lane = t & 63;
    const int qr16 = lane & 15, quad = lane >> 4;

    __shared__ u16 Ks[64 * 40];    // [key][dim 0..31 of head pair], stride 40
    __shared__ u16 VTs[32 * 76];   // [dim 0..31][key], stride 76 (bank-safe)
    __shared__ u16 AWs[64 * 72];   // [qrow 0..63][key 0..63] bf16 (ez)

    const int qrow_l = w * 16 + qr16;                 // block-local qrow
    const long long qrow_g = b * 1024 + n0 + qrow_l;  // global qrow
    const float inv0 = 1.f / rowsum[qrow_g];

    f16x4 qf[2];
#pragma unroll
    for (int hh = 0; hh < 2; ++hh)
        qf[hh] = *(const f16x4*)&qkv[qrow_g * 384 + (h0 + hh) * 16 + quad * 4];

    f32x4 accO[2] = {};
    float lacc[2] = {0.f, 0.f};

    for (int st = 0; st < 16; ++st) {
        const int kb = st * 64;
        __syncthreads();
        // stage K (64 keys x 32 dims) b128: key = t>>2, c8 = t&3
        {
            const int key = t >> 2, c8 = t & 3;
            *(uint4*)&Ks[key * 40 + c8 * 8] =
                *(const uint4*)&qkv[((long long)(b * 1024 + kb + key)) * 384 + 128 + h0 * 16 + c8 * 8];
            // stage V transposed: VTs[dim][key]; write bank-step 16 -> <=2-way
            const f16* vsrc = &qkv[((long long)(b * 1024 + kb + key)) * 384 + 256 + h0 * 16 + c8 * 8];
            f16x4 v0 = *(const f16x4*)vsrc;
            f16x4 v1 = *(const f16x4*)(vsrc + 4);
            const int d0 = c8 * 8;
#pragma unroll
            for (int i = 0; i < 4; ++i) {
                VTs[(d0 + i) * 76 + key] = ((const u16*)&v0)[i];
                VTs[(d0 + 4 + i) * 76 + key] = ((const u16*)&v1)[i];
            }
        }
        // stage AW (64 qrows x 64 keys) b128
#pragma unroll
        for (int rr = 0; rr < 2; ++rr) {
            int idx = rr * 256 + t;
            int row = idx >> 3, c16 = idx & 7;
            *(uint4*)&AWs[row * 72 + c16 * 8] =
                *(const uint4*)&ez[((long long)(b * 1024 + n0 + row)) * 1024 + kb + c16 * 8];
        }
        __syncthreads();

#pragma unroll 2
        for (int kt = 0; kt < 4; ++kt) {
            // aw C-init: lane holds (qrow=qr16, keys kt*16+quad*4+r)
            ushort4 ue = *(const ushort4*)&AWs[qrow_l * 72 + kt * 16 + quad * 4];
            f32x4 aw0;
            aw0[0] = b2f(ue.x) * inv0; aw0[1] = b2f(ue.y) * inv0;
            aw0[2] = b2f(ue.z) * inv0; aw0[3] = b2f(ue.w) * inv0;
#pragma unroll
            for (int hh = 0; hh < 2; ++hh) {
                f16x4 kf = *(const f16x4*)&Ks[(kt * 16 + qr16) * 40 + hh * 16 + quad * 4];
                f32x4 s4 = MFMA16(kf, qf[hh], aw0);
                float p0 = __expf(s4[0]), p1 = __expf(s4[1]);
                float p2 = __expf(s4[2]), p3 = __expf(s4[3]);
                lacc[hh] += (p0 + p1) + (p2 + p3);
                f16x4 pf;
                pf[0] = (f16)p0; pf[1] = (f16)p1; pf[2] = (f16)p2; pf[3] = (f16)p3;
                f16x4 vf = *(const f16x4*)&VTs[(hh * 16 + qr16) * 76 + kt * 16 + quad * 4];
                accO[hh] = MFMA16(vf, pf, accO[hh]);
            }
        }
    }
    // finalize: l over quads, store o normalized as bf16
#pragma unroll
    for (int hh = 0; hh < 2; ++hh) {
        float l = lacc[hh];
        l += __shfl_xor(l, 16);
        l += __shfl_xor(l, 32);
        float inv = 1.f / l;
        ushort4 st4;
        st4.x = f2b(accO[hh][0] * inv);
        st4.y = f2b(accO[hh][1] * inv);
        st4.z = f2b(accO[hh][2] * inv);
        st4.w = f2b(accO[hh][3] * inv);
        *(ushort4*)&ob[qrow_g * 128 + (h0 + hh) * 16 + quad * 4] = st4;
    }
}

// -------- out = ob @ WcombTb^T + bcomb (byte-identical to R30) --------
__global__ __launch_bounds__(256)
void mfma_out(const u16* __restrict__ A, const u16* __restrict__ Bb,
              const float* __restrict__ bias, float* __restrict__ C) {
    const int m0 = blockIdx.x * 128;
    const int t = threadIdx.x;
    const int wave = t >> 6, lane = t & 63;
    const int wm = (wave >> 1) * 64, wn = (wave & 1) * 64;
    const int m16 = lane & 15, kq = lane >> 4;
    f32x4 acc[4][4] = {};

#pragma unroll
    for (int kc = 0; kc < 4; ++kc) {
        bf16x8 af[4], bf[4];
#pragma unroll
        for (int i = 0; i < 4; ++i)
            af[i] = *(const bf16x8*)&A[(long long)(m0 + wm + i * 16 + m16) * 128 + kc * 32 + kq * 8];
#pragma unroll
        for (int j = 0; j < 4; ++j)
            bf[j] = *(const bf16x8*)&Bb[(long long)(wn + j * 16 + m16) * 128 + kc * 32 + kq * 8];
#pragma unroll
        for (int i = 0; i < 4; ++i)
#pragma unroll
            for (int j = 0; j < 4; ++j)
                acc[i][j] = MFMAB(af[i], bf[j], acc[i][j]);
    }
#pragma unroll
    for (int i = 0; i < 4; ++i) {
#pragma unroll
        for (int r = 0; r < 4; ++r) {
            long long row = m0 + wm + i * 16 + kq * 4 + r;
#pragma unroll
            for (int j = 0; j < 4; ++j) {
                int col = wn + j * 16 + m16;
                C[row * 128 + col] = acc[i][j][r] + bias[col];
            }
        }
    }
}

extern "C" void kernel_launch(void* const* d_in, const int* in_sizes, int n_in,
                              void* d_out, int out_size, void* d_ws, size_t ws_size,
                              hipStream_t stream) {
    (void)in_sizes; (void)n_in; (void)out_size; (void)ws_size;
    const float* H    = (const float*)d_in[0];
    const float* Aadj = (const float*)d_in[1];
    const float* Wlin = (const float*)d_in[2];
    const float* blin = (const float*)d_in[3];
    const float* Win  = (const float*)d_in[4];
    const float* bin  = (const float*)d_in[5];
    const float* Wout = (const float*)d_in[6];
    const float* bout = (const float*)d_in[7];
    const float* Wfin = (const float*)d_in[8];
    const float* bfin = (const float*)d_in[9];
    float* out = (float*)d_out;
    char* ws = (char*)d_ws;

    u16*   WinTb   = (u16*)(ws + 0);          // 96 KB bf16
    u16*   WcombTb = (u16*)(ws + 98304);      // 32 KB bf16
    float* bcomb   = (float*)(ws + 131072);   // 512 B
    float* rowsum  = (float*)(ws + 131584);   // 32 KB
    u16*   Hpb     = (u16*)(ws + 262144);     // 2 MB bf16
    f16*   qkv     = (f16*)(ws + 2359296);    // 6 MB (q f16*0.25 | k f16 | v f16)
    u16*   ob      = (u16*)(ws + 8650752);    // 2 MB bf16 normalized o
    u16*   ez      = (u16*)(ws + 12845056);   // 16 MB bf16 exp(z)
    // total ~29 MB

    // prep: Hp MFMA (64 blocks) + weight transposes/combine (320 blocks)
    prep_hp<<<384, 256, 0, stream>>>(H, Wlin, Win, Wout, Wfin, bout, bfin,
                                     blin, WinTb, WcombTb, bcomb, rowsum, Hpb);
    // merged: ez-gate (512 blocks, direct Aadj gate) + qkv f16 (192 blocks)
    mfma_qkvz<<<704, 256, 0, stream>>>(Hpb, WinTb, bin, qkv, Aadj, ez, rowsum);
    // flash v1 body, XCD-swizzled 1D grid (hpair siblings share an XCD's L2)
    flash_mfma<<<512, 256, 0, stream>>>(qkv, ez, rowsum, ob);
    // out = ob @ WcombTb^T + bcomb  (MFMA)
    mfma_out<<<64, 256, 0, stream>>>(ob, WcombTb, bcomb, out);
}